// Round 1
// baseline (694.156 us; speedup 1.0000x reference)
//
#include <hip/hip_runtime.h>
#include <math.h>

// Problem constants
constexpr int B_ = 4;
constexpr int C_ = 192;
constexpr int N_ = 3136;
constexpr int M_ = 3136;
constexpr int K_ = 9;

// Tiling
constexpr int BN = 32;    // rows per block
constexpr int BM = 128;   // cols per m-tile
constexpr int BK = 64;    // k chunk for B staging
constexpr int NMT = 25;   // ceil(3136/128) m-tiles (last is half-masked)
constexpr int DSTRIDE = BM + 1; // padded dtile stride (bank-conflict)

// -------- normalization kernel: inv-norm + post-norm sum of squares --------
__global__ __launch_bounds__(256) void norm_kernel(const float* __restrict__ src,
                                                   float* __restrict__ invn,
                                                   float* __restrict__ sq) {
  int i = blockIdx.x * 256 + threadIdx.x;
  if (i >= B_ * N_) return;
  int b = i / N_, n = i - b * N_;
  const float* p = src + (size_t)b * C_ * N_ + n;
  float s = 0.f;
  for (int c = 0; c < C_; ++c) { float v = p[(size_t)c * N_]; s += v * v; }
  float d = fmaxf(sqrtf(s), 1e-12f);
  float inv = 1.0f / d;
  // reference computes x2 = sum(xn*xn) AFTER normalization; replicate that
  float s2 = 0.f;
  for (int c = 0; c < C_; ++c) { float v = p[(size_t)c * N_] * inv; s2 += v * v; }
  invn[i] = inv;
  sq[i] = s2;
}

// -------- fused distance-GEMM + streaming top-9 --------
__global__ __launch_bounds__(256, 2) void knn_kernel(
    const float* __restrict__ x, const float* __restrict__ y,
    const float* __restrict__ rp,
    const float* __restrict__ invnx, const float* __restrict__ x2a,
    const float* __restrict__ invny, const float* __restrict__ y2a,
    int* __restrict__ out) {
  // LDS carve: As (192x32) | Bs (64x128) | dtile (32x129)
  __shared__ __align__(16) float smem[C_ * BN + BK * BM + BN * DSTRIDE];
  float* As = smem;                    // 6144 floats
  float* Bs = smem + C_ * BN;          // 8192 floats
  float* dtile = Bs + BK * BM;         // 4128 floats
  // merge buffers alias Bs (only used after all GEMM work)
  float* mval = Bs;                    // 32*72 floats
  int* midx = (int*)(Bs + BN * 72);    // 32*72 ints

  const int tid = threadIdx.x;
  const int trow = tid >> 5;   // 0..7  -> rows trow*4..+3
  const int tcol = tid & 31;   // 0..31 -> cols tcol*4..+3
  const int b = blockIdx.y;
  const int n0 = blockIdx.x * BN;

  const float* xb = x + (size_t)b * C_ * N_;
  const float* yb = y + (size_t)b * C_ * N_;
  const float* invx = invnx + b * N_;
  const float* invy = invny + b * N_;
  const float* x2b = x2a + b * N_;
  const float* y2b = y2a + b * N_;

  // ---- stage full-K A tile once (normalized), float4 ----
  {
    const float4* invx4 = (const float4*)(invx + n0);
#pragma unroll
    for (int i = 0; i < 6; ++i) {
      int f = tid + i * 256;           // float4 index, 1536 total
      int c = f >> 3;                  // 8 float4 per row of 32
      int nq = f & 7;
      float4 v = *(const float4*)(xb + (size_t)c * N_ + n0 + nq * 4);
      float4 w = invx4[nq];
      v.x *= w.x; v.y *= w.y; v.z *= w.z; v.w *= w.w;
      ((float4*)As)[f] = v;
    }
  }

  // streaming per-thread top-9 (sorted ascending), static indices only
  float cv0 = INFINITY, cv1 = INFINITY, cv2 = INFINITY, cv3 = INFINITY, cv4 = INFINITY,
        cv5 = INFINITY, cv6 = INFINITY, cv7 = INFINITY, cv8 = INFINITY;
  int ci0 = 0x7fffffff, ci1 = 0x7fffffff, ci2 = 0x7fffffff, ci3 = 0x7fffffff, ci4 = 0x7fffffff,
      ci5 = 0x7fffffff, ci6 = 0x7fffffff, ci7 = 0x7fffffff, ci8 = 0x7fffffff;

  const int srow = tid >> 3;         // topk role: row 0..31
  const int scol0 = (tid & 7) * 16;  // 16 cols per topk thread

  for (int mt = 0; mt < NMT; ++mt) {
    const int m0 = mt * BM;
    float acc[4][4];
#pragma unroll
    for (int rr = 0; rr < 4; ++rr)
#pragma unroll
      for (int cc = 0; cc < 4; ++cc) acc[rr][cc] = 0.f;

    for (int kc = 0; kc < C_ / BK; ++kc) {
      __syncthreads();  // prior Bs use + prior dtile scan complete
      // stage Bs[64][128] normalized, float4
      const float* ybk = yb + (size_t)kc * BK * N_;
#pragma unroll
      for (int i = 0; i < 8; ++i) {
        int f = tid + i * 256;         // float4 index, 2048 total
        int k = f >> 5;                // 32 float4 per row of 128
        int mq = f & 31;
        int gm = m0 + mq * 4;
        float4 v = {0.f, 0.f, 0.f, 0.f};
        if (gm < M_) {
          v = *(const float4*)(ybk + (size_t)k * N_ + gm);
          float4 w = *(const float4*)(invy + gm);
          v.x *= w.x; v.y *= w.y; v.z *= w.z; v.w *= w.w;
        }
        ((float4*)Bs)[f] = v;
      }
      __syncthreads();
      const float* Ak = As + kc * BK * BN;
#pragma unroll 8
      for (int k = 0; k < BK; ++k) {
        float4 a = *(const float4*)(Ak + k * BN + trow * 4);
        float4 bq = *(const float4*)(Bs + k * BM + tcol * 4);
        acc[0][0] = fmaf(a.x, bq.x, acc[0][0]);
        acc[0][1] = fmaf(a.x, bq.y, acc[0][1]);
        acc[0][2] = fmaf(a.x, bq.z, acc[0][2]);
        acc[0][3] = fmaf(a.x, bq.w, acc[0][3]);
        acc[1][0] = fmaf(a.y, bq.x, acc[1][0]);
        acc[1][1] = fmaf(a.y, bq.y, acc[1][1]);
        acc[1][2] = fmaf(a.y, bq.z, acc[1][2]);
        acc[1][3] = fmaf(a.y, bq.w, acc[1][3]);
        acc[2][0] = fmaf(a.z, bq.x, acc[2][0]);
        acc[2][1] = fmaf(a.z, bq.y, acc[2][1]);
        acc[2][2] = fmaf(a.z, bq.z, acc[2][2]);
        acc[2][3] = fmaf(a.z, bq.w, acc[2][3]);
        acc[3][0] = fmaf(a.w, bq.x, acc[3][0]);
        acc[3][1] = fmaf(a.w, bq.y, acc[3][1]);
        acc[3][2] = fmaf(a.w, bq.z, acc[3][2]);
        acc[3][3] = fmaf(a.w, bq.w, acc[3][3]);
      }
    }

    // ---- epilogue: dist = sqrt(max(x2+y2-2*dot,0)) + rp ----
    const int gm0 = m0 + tcol * 4;
    const bool valid = gm0 < M_;   // gm0 % 4 == 0, M_ % 4 == 0 -> whole float4 valid
    float y2r[4] = {0.f, 0.f, 0.f, 0.f};
    if (valid) {
      float4 t = *(const float4*)(y2b + gm0);
      y2r[0] = t.x; y2r[1] = t.y; y2r[2] = t.z; y2r[3] = t.w;
    }
#pragma unroll
    for (int rr = 0; rr < 4; ++rr) {
      int r = trow * 4 + rr;
      int n = n0 + r;
      float x2v = x2b[n];
      float rpr[4] = {0.f, 0.f, 0.f, 0.f};
      if (valid) {
        float4 t = *(const float4*)(rp + (size_t)n * M_ + gm0);
        rpr[0] = t.x; rpr[1] = t.y; rpr[2] = t.z; rpr[3] = t.w;
      }
#pragma unroll
      for (int cc = 0; cc < 4; ++cc) {
        float s = x2v + y2r[cc] - 2.0f * acc[rr][cc];
        float dd = valid ? (sqrtf(fmaxf(s, 0.f)) + rpr[cc]) : INFINITY;
        dtile[r * DSTRIDE + tcol * 4 + cc] = dd;
      }
    }
    __syncthreads();

    // ---- streaming top-9 scan (16 cols per thread, ascending idx) ----
    const int sbase = srow * DSTRIDE + scol0;
#pragma unroll
    for (int j = 0; j < 16; ++j) {
      float v = dtile[sbase + j];
      if (v < cv8) {
        cv8 = v;
        ci8 = m0 + scol0 + j;
        // unrolled bubble insert (static indices -> stays in VGPRs)
#define SWAP_STEP(A, IA, Bv, IB)                                        \
        {                                                               \
          bool sw = (A < Bv) || (A == Bv && IA < IB);                   \
          if (sw) { float tv = A; A = Bv; Bv = tv; int ti = IA; IA = IB; IB = ti; } \
        }
        SWAP_STEP(cv8, ci8, cv7, ci7)
        SWAP_STEP(cv7, ci7, cv6, ci6)
        SWAP_STEP(cv6, ci6, cv5, ci5)
        SWAP_STEP(cv5, ci5, cv4, ci4)
        SWAP_STEP(cv4, ci4, cv3, ci3)
        SWAP_STEP(cv3, ci3, cv2, ci2)
        SWAP_STEP(cv2, ci2, cv1, ci1)
        SWAP_STEP(cv1, ci1, cv0, ci0)
#undef SWAP_STEP
      }
    }
  }

  // ---- final merge: 8 sorted lists of 9 per row -> top 9 ----
  __syncthreads();  // all GEMM (Bs) use finished; safe to alias
  {
    int base = srow * 72 + (tid & 7) * 9;
    mval[base + 0] = cv0; midx[base + 0] = ci0;
    mval[base + 1] = cv1; midx[base + 1] = ci1;
    mval[base + 2] = cv2; midx[base + 2] = ci2;
    mval[base + 3] = cv3; midx[base + 3] = ci3;
    mval[base + 4] = cv4; midx[base + 4] = ci4;
    mval[base + 5] = cv5; midx[base + 5] = ci5;
    mval[base + 6] = cv6; midx[base + 6] = ci6;
    mval[base + 7] = cv7; midx[base + 7] = ci7;
    mval[base + 8] = cv8; midx[base + 8] = ci8;
  }
  __syncthreads();
  if (tid < BN) {
    int r = tid;
    int n = n0 + r;
    int ob = (b * N_ + n) * K_;
    float pv = -INFINITY;
    int pi = -1;
    for (int k = 0; k < K_; ++k) {
      float bv = INFINITY;
      int bi = 0x7fffffff;
      for (int s = 0; s < 72; ++s) {
        float v = mval[r * 72 + s];
        int id = midx[r * 72 + s];
        bool gt = (v > pv) || (v == pv && id > pi);
        bool lt = (v < bv) || (v == bv && id < bi);
        if (gt && lt) { bv = v; bi = id; }
      }
      out[ob + k] = bi;
      out[B_ * N_ * K_ + ob + k] = n;  // center index
      pv = bv; pi = bi;
    }
  }
}

extern "C" void kernel_launch(void* const* d_in, const int* in_sizes, int n_in,
                              void* d_out, int out_size, void* d_ws, size_t ws_size,
                              hipStream_t stream) {
  const float* x = (const float*)d_in[0];
  const float* y = (const float*)d_in[1];
  const float* rp = (const float*)d_in[2];
  int* out = (int*)d_out;

  float* ws = (float*)d_ws;
  float* invnx = ws;
  float* x2 = ws + B_ * N_;
  float* invny = ws + 2 * B_ * N_;
  float* y2 = ws + 3 * B_ * N_;

  norm_kernel<<<(B_ * N_ + 255) / 256, 256, 0, stream>>>(x, invnx, x2);
  norm_kernel<<<(B_ * N_ + 255) / 256, 256, 0, stream>>>(y, invny, y2);
  knn_kernel<<<dim3(N_ / BN, B_), 256, 0, stream>>>(x, y, rp, invnx, x2, invny, y2, out);
}

// Round 2
// 410.107 us; speedup vs baseline: 1.6926x; 1.6926x over previous
//
#include <hip/hip_runtime.h>
#include <math.h>

// Problem constants
constexpr int B_ = 4;
constexpr int C_ = 192;
constexpr int N_ = 3136;
constexpr int K_ = 9;
constexpr int NG = N_ / 16;     // 196 row-groups of 16
constexpr int SPLIT = 1568;     // M split width (2 splits)
constexpr int NMT = 13;         // 128-col tiles per split (last partial: 32 cols)

typedef _Float16 half8 __attribute__((ext_vector_type(8)));
typedef float f32x4 __attribute__((ext_vector_type(4)));
typedef unsigned long long u64;
typedef unsigned int u32;

// ---------------- norm: inv-norm + post-norm sum of squares ----------------
__global__ __launch_bounds__(256) void norm_kernel(const float* __restrict__ src,
                                                   float* __restrict__ invn,
                                                   float* __restrict__ sq) {
  int i = blockIdx.x * 256 + threadIdx.x;
  if (i >= B_ * N_) return;
  int b = i / N_, n = i - b * N_;
  const float* p = src + (size_t)b * C_ * N_ + n;
  float s = 0.f;
  for (int c = 0; c < C_; ++c) { float v = p[(size_t)c * N_]; s += v * v; }
  float d = fmaxf(sqrtf(s), 1e-12f);
  float inv = 1.0f / d;
  float s2 = 0.f;
  for (int c = 0; c < C_; ++c) { float v = p[(size_t)c * N_] * inv; s2 += v * v; }
  invn[i] = inv;
  sq[i] = s2;
}

// ------- transpose + normalize: fp32 [b][n][c] rows + f16 MFMA-swizzled -------
// f16 swizzle: chunk (b, g=n>>4, kc=c>>5) of 1KB; slot = (n&15)|(((c>>3)&3)<<4);
// element = c&7.  This is exactly the 16x16x32 A/B fragment lane order.
__global__ __launch_bounds__(256) void prep_kernel(const float* __restrict__ src,
                                                   const float* __restrict__ invn,
                                                   float* __restrict__ t32,
                                                   _Float16* __restrict__ t16sw) {
  __shared__ float tile[32 * 33];
  const int tx = threadIdx.x, ty = threadIdx.y;
  const int n0 = blockIdx.x * 32, c0 = blockIdx.y * 32, b = blockIdx.z;
  const float* sp = src + (size_t)b * C_ * N_;
#pragma unroll
  for (int i = 0; i < 4; ++i) {
    int c_loc = ty + i * 8;
    tile[c_loc * 33 + tx] = sp[(size_t)(c0 + c_loc) * N_ + n0 + tx];
  }
  __syncthreads();
  // fp32 transposed+normalized write (coalesced in c)
#pragma unroll
  for (int i = 0; i < 4; ++i) {
    int n_loc = ty + i * 8;
    int n = n0 + n_loc;
    float v = tile[tx * 33 + n_loc] * invn[b * N_ + n];
    t32[(size_t)(b * N_ + n) * C_ + c0 + tx] = v;
  }
  // f16 swizzled write (16B per thread)
  int tid = ty * 32 + tx;
  if (tid < 128) {
    int n_loc = tid >> 2, cq = tid & 3;
    int n = n0 + n_loc;
    float inv = invn[b * N_ + n];
    int kc = c0 >> 5;                 // one kc per block (c0 multiple of 32)
    int slot = (n & 15) | (cq << 4);
    half8 h;
#pragma unroll
    for (int e = 0; e < 8; ++e)
      h[e] = (_Float16)(tile[(cq * 8 + e) * 33 + n_loc] * inv);
    *(half8*)(t16sw + ((size_t)((b * NG + (n >> 4)) * 6 + kc) * 64 + slot) * 8) = h;
  }
}

// ---------------- fused f16-MFMA distance GEMM + streaming top-16 ----------------
__device__ __forceinline__ u32 fkey(float f) {
  u32 u = __float_as_uint(f);
  return u ^ (u32)(((int)u >> 31) | 0x80000000);
}

#define SWP(a, b) { u64 _lo = (b < a) ? b : a; u64 _hi = (b < a) ? a : b; a = _lo; b = _hi; }

#define BUBBLE(mn)                                                     \
  { K15 = mn;                                                          \
    SWP(K14, K15) SWP(K13, K14) SWP(K12, K13) SWP(K11, K12)            \
    SWP(K10, K11) SWP(K9, K10)  SWP(K8, K9)   SWP(K7, K8)              \
    SWP(K6, K7)   SWP(K5, K6)   SWP(K4, K5)   SWP(K3, K4)              \
    SWP(K2, K3)   SWP(K1, K2)   SWP(K0, K1) }

#define MERGESTEP(dist)                                                        \
  { u64 o0  = __shfl_xor(K15, dist), o1  = __shfl_xor(K14, dist);              \
    u64 o2  = __shfl_xor(K13, dist), o3  = __shfl_xor(K12, dist);              \
    u64 o4  = __shfl_xor(K11, dist), o5  = __shfl_xor(K10, dist);              \
    u64 o6  = __shfl_xor(K9, dist),  o7  = __shfl_xor(K8, dist);               \
    u64 o8  = __shfl_xor(K7, dist),  o9  = __shfl_xor(K6, dist);               \
    u64 o10 = __shfl_xor(K5, dist),  o11 = __shfl_xor(K4, dist);               \
    u64 o12 = __shfl_xor(K3, dist),  o13 = __shfl_xor(K2, dist);               \
    u64 o14 = __shfl_xor(K1, dist),  o15 = __shfl_xor(K0, dist);               \
    K0 = K0 < o0 ? K0 : o0;     K1 = K1 < o1 ? K1 : o1;                        \
    K2 = K2 < o2 ? K2 : o2;     K3 = K3 < o3 ? K3 : o3;                        \
    K4 = K4 < o4 ? K4 : o4;     K5 = K5 < o5 ? K5 : o5;                        \
    K6 = K6 < o6 ? K6 : o6;     K7 = K7 < o7 ? K7 : o7;                        \
    K8 = K8 < o8 ? K8 : o8;     K9 = K9 < o9 ? K9 : o9;                        \
    K10 = K10 < o10 ? K10 : o10; K11 = K11 < o11 ? K11 : o11;                  \
    K12 = K12 < o12 ? K12 : o12; K13 = K13 < o13 ? K13 : o13;                  \
    K14 = K14 < o14 ? K14 : o14; K15 = K15 < o15 ? K15 : o15;                  \
    /* bitonic re-sort, d=8,4,2,1 */                                           \
    SWP(K0, K8) SWP(K1, K9) SWP(K2, K10) SWP(K3, K11)                          \
    SWP(K4, K12) SWP(K5, K13) SWP(K6, K14) SWP(K7, K15)                        \
    SWP(K0, K4) SWP(K1, K5) SWP(K2, K6) SWP(K3, K7)                            \
    SWP(K8, K12) SWP(K9, K13) SWP(K10, K14) SWP(K11, K15)                      \
    SWP(K0, K2) SWP(K1, K3) SWP(K4, K6) SWP(K5, K7)                            \
    SWP(K8, K10) SWP(K9, K11) SWP(K12, K14) SWP(K13, K15)                      \
    SWP(K0, K1) SWP(K2, K3) SWP(K4, K5) SWP(K6, K7)                            \
    SWP(K8, K9) SWP(K10, K11) SWP(K12, K13) SWP(K14, K15) }

__global__ __launch_bounds__(256, 3) void gemm_topk(
    const _Float16* __restrict__ xsw, const _Float16* __restrict__ ysw,
    const float* __restrict__ rp, const float* __restrict__ x2a,
    const float* __restrict__ y2a, int* __restrict__ cidx) {
  __shared__ __align__(16) _Float16 As[4 * 6 * 512];   // 24 KB, resident all sweep
  __shared__ __align__(16) _Float16 Bs[2 * 8 * 512];   // 16 KB double-buffered
  __shared__ __align__(16) float scr_s[4 * 16 * 20];   // per-wave C-fragment scratch

  const int tid = threadIdx.x, w = tid >> 6, l = tid & 63;
  const int b = blockIdx.z, s = blockIdx.y, n0 = blockIdx.x * 64;

  // ---- stage A once: wave w stages its own 16-row group, all 6 k-chunks ----
  {
    const _Float16* srcA = xsw + (size_t)((b * NG + (n0 >> 4) + w) * 6) * 512;
#pragma unroll
    for (int kc = 0; kc < 6; ++kc)
      *(half8*)(As + (w * 6 + kc) * 512 + l * 8) = *(const half8*)(srcA + kc * 512 + l * 8);
  }

  auto stageB = [&](int mt, int kc, int bufn) {
    int gb = (s * SPLIT + mt * 128) >> 4;
#pragma unroll
    for (int gi = 0; gi < 2; ++gi) {
      int g = w + gi * 4;
      int mg = gb + g; mg = mg < NG ? mg : NG - 1;   // clamp (masked later)
      *(half8*)(Bs + bufn * 4096 + g * 512 + l * 8) =
          *(const half8*)(ysw + (size_t)((b * NG + mg) * 6 + kc) * 512 + l * 8);
    }
  };
  stageB(0, 0, 0);

  // per-lane streaming top-16 as packed u64 keys (val<<32 | idx)
  u64 K0 = ~0ull, K1 = ~0ull, K2 = ~0ull, K3 = ~0ull, K4 = ~0ull, K5 = ~0ull,
      K6 = ~0ull, K7 = ~0ull, K8 = ~0ull, K9 = ~0ull, K10 = ~0ull, K11 = ~0ull,
      K12 = ~0ull, K13 = ~0ull, K14 = ~0ull, K15 = ~0ull;

  const int rr_ = l >> 2, qq = l & 3;          // scan role: row 0..15, col-quad
  const int colw = l & 15, rowq = (l >> 4) * 4; // C-frag role
  const int n_glob = n0 + w * 16 + rr_;
  const float x2v = x2a[b * N_ + n_glob];
  float* scr = scr_s + w * 320;

  int buf = 0;
  for (int mt = 0; mt < NMT; ++mt) {
    f32x4 acc[8];
#pragma unroll
    for (int j = 0; j < 8; ++j) acc[j] = (f32x4){0.f, 0.f, 0.f, 0.f};

    for (int kc = 0; kc < 6; ++kc) {
      __syncthreads();
      if (kc < 5) stageB(mt, kc + 1, buf ^ 1);
      else if (mt + 1 < NMT) stageB(mt + 1, 0, buf ^ 1);
      half8 a = *(const half8*)(As + (w * 6 + kc) * 512 + l * 8);
#pragma unroll
      for (int j = 0; j < 8; ++j) {
        half8 bf = *(const half8*)(Bs + buf * 4096 + j * 512 + l * 8);
        acc[j] = __builtin_amdgcn_mfma_f32_16x16x32_f16(a, bf, acc[j], 0, 0, 0);
      }
      buf ^= 1;
    }

    // ---- epilogue: per 16-col fragment group, via per-wave LDS scratch ----
    const int m0 = s * SPLIT + mt * 128;
#pragma unroll
    for (int j = 0; j < 8; ++j) {
      if (mt * 128 + j * 16 < SPLIT) {   // wave-uniform validity (SPLIT%16==0)
#pragma unroll
        for (int e = 0; e < 4; ++e) scr[(rowq + e) * 20 + colw] = acc[j][e];
        f32x4 dot = *(const f32x4*)(scr + rr_ * 20 + qq * 4);
        const int mg = m0 + j * 16 + qq * 4;
        f32x4 y2v = *(const f32x4*)(y2a + b * N_ + mg);
        f32x4 rpv = *(const f32x4*)(rp + (size_t)n_glob * N_ + mg);
        float d0 = sqrtf(fmaxf(x2v + y2v[0] - 2.f * dot[0], 0.f)) + rpv[0];
        float d1 = sqrtf(fmaxf(x2v + y2v[1] - 2.f * dot[1], 0.f)) + rpv[1];
        float d2 = sqrtf(fmaxf(x2v + y2v[2] - 2.f * dot[2], 0.f)) + rpv[2];
        float d3 = sqrtf(fmaxf(x2v + y2v[3] - 2.f * dot[3], 0.f)) + rpv[3];
        u64 kk0 = ((u64)fkey(d0) << 32) | (u32)(mg + 0);
        u64 kk1 = ((u64)fkey(d1) << 32) | (u32)(mg + 1);
        u64 kk2 = ((u64)fkey(d2) << 32) | (u32)(mg + 2);
        u64 kk3 = ((u64)fkey(d3) << 32) | (u32)(mg + 3);
        for (;;) {
          u64 ma = kk0 < kk1 ? kk0 : kk1;
          u64 mb = kk2 < kk3 ? kk2 : kk3;
          u64 mn = ma < mb ? ma : mb;
          if (!__any(mn < K15)) break;
          if (mn < K15) {
            BUBBLE(mn);
            kk0 = (kk0 == mn) ? ~0ull : kk0;
            kk1 = (kk1 == mn) ? ~0ull : kk1;
            kk2 = (kk2 == mn) ? ~0ull : kk2;
            kk3 = (kk3 == mn) ? ~0ull : kk3;
          }
        }
      }
    }
  }

  // ---- cross-lane merge: 4 lanes per row -> row top-16 (bitonic) ----
  MERGESTEP(1)
  MERGESTEP(2)
  if (qq == 0) {
    size_t base = ((size_t)(b * N_ + n_glob) * 2 + s) * 16;
    int* o = cidx + base;
    o[0] = (int)(u32)K0;   o[1] = (int)(u32)K1;   o[2] = (int)(u32)K2;
    o[3] = (int)(u32)K3;   o[4] = (int)(u32)K4;   o[5] = (int)(u32)K5;
    o[6] = (int)(u32)K6;   o[7] = (int)(u32)K7;   o[8] = (int)(u32)K8;
    o[9] = (int)(u32)K9;   o[10] = (int)(u32)K10; o[11] = (int)(u32)K11;
    o[12] = (int)(u32)K12; o[13] = (int)(u32)K13; o[14] = (int)(u32)K14;
    o[15] = (int)(u32)K15;
  }
}

// ---------------- exact fp32 refine: 32 candidates -> top-9 ----------------
__global__ __launch_bounds__(256) void refine_kernel(
    const float* __restrict__ xt, const float* __restrict__ yt,
    const float* __restrict__ rp, const float* __restrict__ x2a,
    const float* __restrict__ y2a, const int* __restrict__ cidx,
    int* __restrict__ out) {
  __shared__ float vals[8][32];
  __shared__ int idxs[8][32];
  const int t = threadIdx.x, r = t >> 5, j = t & 31;
  const int b = blockIdx.y, n = blockIdx.x * 8 + r;
  int m = cidx[(size_t)(b * N_ + n) * 32 + j];
  float d;
  if ((u32)m < (u32)N_) {
    const float* xr = xt + (size_t)(b * N_ + n) * C_;
    const float* yr = yt + (size_t)(b * N_ + m) * C_;
    float acc = 0.f;
    for (int c = 0; c < C_; ++c) acc = fmaf(xr[c], yr[c], acc);
    float ss = x2a[b * N_ + n] + y2a[b * N_ + m] - 2.f * acc;
    d = sqrtf(fmaxf(ss, 0.f)) + rp[(size_t)n * N_ + m];
  } else {
    d = INFINITY; m = 0x7fffffff;
  }
  vals[r][j] = d;
  idxs[r][j] = m;
  __syncthreads();
  if (t < 8) {
    int n2 = blockIdx.x * 8 + t;
    int ob = (b * N_ + n2) * K_;
    float pv = -INFINITY; int pi = -1;
    for (int k = 0; k < K_; ++k) {
      float bv = INFINITY; int bi = 0x7fffffff;
      for (int q = 0; q < 32; ++q) {
        float v = vals[t][q]; int id = idxs[t][q];
        bool gt = (v > pv) || (v == pv && id > pi);
        bool lt = (v < bv) || (v == bv && id < bi);
        if (gt && lt) { bv = v; bi = id; }
      }
      out[ob + k] = bi;
      out[B_ * N_ * K_ + ob + k] = n2;
      pv = bv; pi = bi;
    }
  }
}

extern "C" void kernel_launch(void* const* d_in, const int* in_sizes, int n_in,
                              void* d_out, int out_size, void* d_ws, size_t ws_size,
                              hipStream_t stream) {
  const float* x = (const float*)d_in[0];
  const float* y = (const float*)d_in[1];
  const float* rp = (const float*)d_in[2];
  int* out = (int*)d_out;

  char* ws = (char*)d_ws;
  size_t off = 0;
  auto alloc = [&](size_t bytes) { char* p = ws + off; off += (bytes + 255) & ~(size_t)255; return p; };
  float* invnx = (float*)alloc(B_ * N_ * 4);
  float* x2 = (float*)alloc(B_ * N_ * 4);
  float* invny = (float*)alloc(B_ * N_ * 4);
  float* y2 = (float*)alloc(B_ * N_ * 4);
  float* xt32 = (float*)alloc((size_t)B_ * N_ * C_ * 4);
  float* yt32 = (float*)alloc((size_t)B_ * N_ * C_ * 4);
  _Float16* xt16 = (_Float16*)alloc((size_t)B_ * N_ * C_ * 2);
  _Float16* yt16 = (_Float16*)alloc((size_t)B_ * N_ * C_ * 2);
  int* cidx = (int*)alloc((size_t)B_ * N_ * 32 * 4);

  norm_kernel<<<(B_ * N_ + 255) / 256, 256, 0, stream>>>(x, invnx, x2);
  norm_kernel<<<(B_ * N_ + 255) / 256, 256, 0, stream>>>(y, invny, y2);
  prep_kernel<<<dim3(N_ / 32, C_ / 32, B_), dim3(32, 8), 0, stream>>>(x, invnx, xt32, xt16);
  prep_kernel<<<dim3(N_ / 32, C_ / 32, B_), dim3(32, 8), 0, stream>>>(y, invny, yt32, yt16);
  gemm_topk<<<dim3(N_ / 64, 2, B_), 256, 0, stream>>>(xt16, yt16, rp, x2, y2, cidx);
  refine_kernel<<<dim3(N_ / 8, B_), 256, 0, stream>>>(xt32, yt32, rp, x2, y2, cidx, out);
}